// Round 4
// baseline (375.916 us; speedup 1.0000x reference)
//
#include <hip/hip_runtime.h>
#include <math.h>

// MoE gate: logits = hidden[16384,4096] @ gate_w[8,4096]^T -> softmax -> top2 -> renorm.
// Barrier-free streaming, 4 tokens/wave: hidden (256 MiB) read once via nontemporal
// float4 loads; gate_w (128 KB, L2-resident) read from global, amortized over 4 tokens
// so per-CU vector-load traffic is only 3x the HBM share (w-path fully hidden).
// No LDS / no __syncthreads => compiler software-pipelines the whole k-loop.

#define HDIM 4096
#define NEXP 8
#define TOK_PER_WAVE 4
#define WAVES_PER_BLOCK 4
#define TOK_PER_BLOCK (TOK_PER_WAVE * WAVES_PER_BLOCK)   // 16
#define KSTEPS (HDIM / (64 * 4))                          // 16 float4-steps per row

typedef float f32x4 __attribute__((ext_vector_type(4)));

__global__ __launch_bounds__(256, 4) void moe_gate_kernel(
    const float* __restrict__ hidden,   // [n_tokens, 4096]
    const float* __restrict__ gate_w,   // [8, 4096]
    float* __restrict__ out,            // [2*n_tokens weights][2*n_tokens indices-as-float]
    int n_tokens) {
  const int tid  = threadIdx.x;
  const int wave = tid >> 6;
  const int lane = tid & 63;
  const int tbase = blockIdx.x * TOK_PER_BLOCK + wave * TOK_PER_WAVE;
  if (tbase >= n_tokens) return;

  float acc[TOK_PER_WAVE][NEXP];
#pragma unroll
  for (int t = 0; t < TOK_PER_WAVE; ++t)
#pragma unroll
    for (int e = 0; e < NEXP; ++e) acc[t][e] = 0.f;

  const float* hbase = hidden + (size_t)tbase * HDIM;

#pragma unroll 2
  for (int it = 0; it < KSTEPS; ++it) {
    const int koff = (it * 64 + lane) * 4;   // float index; 1 KB/wave contiguous
    f32x4 h4[TOK_PER_WAVE];
#pragma unroll
    for (int t = 0; t < TOK_PER_WAVE; ++t)
      h4[t] = __builtin_nontemporal_load((const f32x4*)(hbase + (size_t)t * HDIM + koff));
#pragma unroll
    for (int e = 0; e < NEXP; ++e) {
      const f32x4 w4 = *(const f32x4*)(gate_w + e * HDIM + koff);
#pragma unroll
      for (int t = 0; t < TOK_PER_WAVE; ++t) {
        acc[t][e] += h4[t].x * w4.x;
        acc[t][e] += h4[t].y * w4.y;
        acc[t][e] += h4[t].z * w4.z;
        acc[t][e] += h4[t].w * w4.w;
      }
    }
  }

  // ---- butterfly allreduce across the 64-lane wave ----
#pragma unroll
  for (int t = 0; t < TOK_PER_WAVE; ++t) {
#pragma unroll
    for (int e = 0; e < NEXP; ++e) {
      float v = acc[t][e];
#pragma unroll
      for (int m = 1; m < 64; m <<= 1) v += __shfl_xor(v, m, 64);
      acc[t][e] = v;
    }
  }

  // ---- lanes 0..3: top-2 + renormalized softmax pair for token tbase+lane ----
  if (lane < TOK_PER_WAVE) {
    const int token = tbase + lane;
    if (token < n_tokens) {
      float l[NEXP];
#pragma unroll
      for (int e = 0; e < NEXP; ++e) {
        float v = acc[0][e];
        if (lane == 1) v = acc[1][e];
        if (lane == 2) v = acc[2][e];
        if (lane == 3) v = acc[3][e];
        l[e] = v;
      }
      // top-1 (strict > keeps lowest index on ties, matching lax.top_k)
      int i1 = 0; float v1 = l[0];
#pragma unroll
      for (int e = 1; e < NEXP; ++e)
        if (l[e] > v1) { v1 = l[e]; i1 = e; }
      // top-2
      int i2 = (i1 == 0) ? 1 : 0; float v2 = l[(i1 == 0) ? 1 : 0];
#pragma unroll
      for (int e = 0; e < NEXP; ++e)
        if (e != i1 && l[e] > v2) { v2 = l[e]; i2 = e; }

      // renormalized top-2 softmax: w1 = e^{v1}/(e^{v1}+e^{v2})
      const float w1 = 1.0f / (1.0f + expf(v2 - v1));
      const float w2 = 1.0f - w1;

      const int nw = 2 * n_tokens;
      out[token * 2 + 0] = w1;
      out[token * 2 + 1] = w2;
      out[nw + token * 2 + 0] = (float)i1;
      out[nw + token * 2 + 1] = (float)i2;
    }
  }
}

extern "C" void kernel_launch(void* const* d_in, const int* in_sizes, int n_in,
                              void* d_out, int out_size, void* d_ws, size_t ws_size,
                              hipStream_t stream) {
  const float* hidden = (const float*)d_in[0];   // [4,4096,4096] fp32
  const float* gate_w = (const float*)d_in[1];   // [8,4096] fp32
  float* out = (float*)d_out;                    // 32768 weights + 32768 indices

  const int n_tokens = in_sizes[0] / HDIM;       // 16384
  const int grid = (n_tokens + TOK_PER_BLOCK - 1) / TOK_PER_BLOCK;  // 1024
  moe_gate_kernel<<<grid, 256, 0, stream>>>(hidden, gate_w, out, n_tokens);
}

// Round 5
// 361.231 us; speedup vs baseline: 1.0407x; 1.0407x over previous
//
#include <hip/hip_runtime.h>
#include <math.h>

// MoE gate: logits = hidden[16384,4096] @ gate_w[8,4096]^T -> softmax -> top2 -> renorm.
// Best-measured variant (R3): barrier-free streaming, 2 tokens/wave.
// hidden (256 MiB) read once with nontemporal float4 loads (don't pollute L2);
// gate_w (128 KB) read per-step from global — L1/L2-resident, never critical-path.
// No LDS, no __syncthreads => compiler software-pipelines the whole k-loop.
// A/B history: LDS-staged+barriers 367 us; TOK=4 376 us; this 363 us total
// (harness reset ~300 us of that; kernel ~55-65 us vs 43 us HBM floor).

#define HDIM 4096
#define NEXP 8
#define TOK_PER_WAVE 2
#define WAVES_PER_BLOCK 4
#define TOK_PER_BLOCK (TOK_PER_WAVE * WAVES_PER_BLOCK)   // 8
#define KSTEPS (HDIM / (64 * 4))                          // 16 float4-steps per row

typedef float f32x4 __attribute__((ext_vector_type(4)));  // clang vector: valid for
                                                          // __builtin_nontemporal_load

__global__ __launch_bounds__(256, 4) void moe_gate_kernel(
    const float* __restrict__ hidden,   // [n_tokens, 4096]
    const float* __restrict__ gate_w,   // [8, 4096]
    float* __restrict__ out,            // [2*n_tokens weights][2*n_tokens indices-as-float]
    int n_tokens) {
  const int tid  = threadIdx.x;
  const int wave = tid >> 6;
  const int lane = tid & 63;
  const int tbase = blockIdx.x * TOK_PER_BLOCK + wave * TOK_PER_WAVE;
  if (tbase >= n_tokens) return;

  float acc[TOK_PER_WAVE][NEXP];
#pragma unroll
  for (int t = 0; t < TOK_PER_WAVE; ++t)
#pragma unroll
    for (int e = 0; e < NEXP; ++e) acc[t][e] = 0.f;

  const float* h0 = hidden + (size_t)tbase * HDIM;
  const float* h1 = h0 + HDIM;

#pragma unroll 2
  for (int it = 0; it < KSTEPS; ++it) {
    const int koff = (it * 64 + lane) * 4;   // float index; 1 KB/wave contiguous
    const f32x4 ha = __builtin_nontemporal_load((const f32x4*)(h0 + koff));
    const f32x4 hb = __builtin_nontemporal_load((const f32x4*)(h1 + koff));
#pragma unroll
    for (int e = 0; e < NEXP; ++e) {
      const f32x4 w4 = *(const f32x4*)(gate_w + e * HDIM + koff);
      acc[0][e] += ha.x * w4.x;
      acc[0][e] += ha.y * w4.y;
      acc[0][e] += ha.z * w4.z;
      acc[0][e] += ha.w * w4.w;
      acc[1][e] += hb.x * w4.x;
      acc[1][e] += hb.y * w4.y;
      acc[1][e] += hb.z * w4.z;
      acc[1][e] += hb.w * w4.w;
    }
  }

  // ---- butterfly allreduce across the 64-lane wave ----
#pragma unroll
  for (int t = 0; t < TOK_PER_WAVE; ++t) {
#pragma unroll
    for (int e = 0; e < NEXP; ++e) {
      float v = acc[t][e];
#pragma unroll
      for (int m = 1; m < 64; m <<= 1) v += __shfl_xor(v, m, 64);
      acc[t][e] = v;
    }
  }

  // ---- lanes 0..1: top-2 + renormalized softmax pair for token tbase+lane ----
  if (lane < TOK_PER_WAVE) {
    const int token = tbase + lane;
    if (token < n_tokens) {
      float l[NEXP];
#pragma unroll
      for (int e = 0; e < NEXP; ++e) {
        float v = acc[0][e];
        if (lane == 1) v = acc[1][e];
        l[e] = v;
      }
      // top-1 (strict > keeps lowest index on ties, matching lax.top_k)
      int i1 = 0; float v1 = l[0];
#pragma unroll
      for (int e = 1; e < NEXP; ++e)
        if (l[e] > v1) { v1 = l[e]; i1 = e; }
      // top-2
      int i2 = (i1 == 0) ? 1 : 0; float v2 = l[(i1 == 0) ? 1 : 0];
#pragma unroll
      for (int e = 0; e < NEXP; ++e)
        if (e != i1 && l[e] > v2) { v2 = l[e]; i2 = e; }

      // renormalized top-2 softmax: w1 = e^{v1}/(e^{v1}+e^{v2})
      const float w1 = 1.0f / (1.0f + expf(v2 - v1));
      const float w2 = 1.0f - w1;

      const int nw = 2 * n_tokens;
      out[token * 2 + 0] = w1;
      out[token * 2 + 1] = w2;
      out[nw + token * 2 + 0] = (float)i1;
      out[nw + token * 2 + 1] = (float)i2;
    }
  }
}

extern "C" void kernel_launch(void* const* d_in, const int* in_sizes, int n_in,
                              void* d_out, int out_size, void* d_ws, size_t ws_size,
                              hipStream_t stream) {
  const float* hidden = (const float*)d_in[0];   // [4,4096,4096] fp32
  const float* gate_w = (const float*)d_in[1];   // [8,4096] fp32
  float* out = (float*)d_out;                    // 32768 weights + 32768 indices

  const int n_tokens = in_sizes[0] / HDIM;       // 16384
  const int grid = (n_tokens + TOK_PER_BLOCK - 1) / TOK_PER_BLOCK;  // 2048
  moe_gate_kernel<<<grid, 256, 0, stream>>>(hidden, gate_w, out, n_tokens);
}